// Round 1
// baseline (1023.523 us; speedup 1.0000x reference)
//
#include <hip/hip_runtime.h>
#include <cstdint>
#include <cstddef>

#define V 50257
#define BLOCK 256
#define UNROLL 8

__device__ __forceinline__ void combine(float& m, float& s, float mo, float so) {
    float m2 = fmaxf(m, mo);
    s = s * __expf(m - m2) + so * __expf(mo - m2);
    m = m2;
}

__device__ __forceinline__ float max4(const float4 v) {
    return fmaxf(fmaxf(v.x, v.y), fmaxf(v.z, v.w));
}

__device__ __forceinline__ float esum4(const float4 v, const float m2) {
    return (__expf(v.x - m2) + __expf(v.y - m2)) + (__expf(v.z - m2) + __expf(v.w - m2));
}

__global__ __launch_bounds__(BLOCK) void sce_row_kernel(
    const float* __restrict__ inputs, const int* __restrict__ targets,
    float* __restrict__ row_out) {
    const int row = blockIdx.x;
    const int tid = threadIdx.x;
    const float* row_ptr = inputs + (size_t)row * V;

    // target gather (thread 0 only; issued early, latency hidden under main loop)
    float xt = 0.0f;
    if (tid == 0) xt = row_ptr[targets[row]];

    // alignment: row start address mod 16 B rotates per row (V % 4 == 1)
    const int misalign = (int)(((size_t)row * V) & 3);
    const int head = (4 - misalign) & 3;
    const int nvec = (V - head) >> 2;
    const int tail_start = head + (nvec << 2);
    const float4* vp = reinterpret_cast<const float4*>(row_ptr + head);

    float m = -INFINITY, s = 0.0f;

    // ---- main: 8-way unrolled chunked online softmax ----
    // 8 independent dwordx4 loads in flight per iteration (128 B/thread),
    // ONE rescale exp per 32 elements instead of one per 4.
    int i = tid;
    for (; i + (UNROLL - 1) * BLOCK < nvec; i += UNROLL * BLOCK) {
        const float4 a0 = vp[i];
        const float4 a1 = vp[i + 1 * BLOCK];
        const float4 a2 = vp[i + 2 * BLOCK];
        const float4 a3 = vp[i + 3 * BLOCK];
        const float4 a4 = vp[i + 4 * BLOCK];
        const float4 a5 = vp[i + 5 * BLOCK];
        const float4 a6 = vp[i + 6 * BLOCK];
        const float4 a7 = vp[i + 7 * BLOCK];

        // chunk max over 32 values (tree; clang fuses to v_max3_f32 where it can)
        const float cm = fmaxf(
            fmaxf(fmaxf(max4(a0), max4(a1)), fmaxf(max4(a2), max4(a3))),
            fmaxf(fmaxf(max4(a4), max4(a5)), fmaxf(max4(a6), max4(a7))));
        const float m2 = fmaxf(m, cm);
        const float r = __expf(m - m2);   // single rescale for the whole chunk
        const float e =
            ((esum4(a0, m2) + esum4(a1, m2)) + (esum4(a2, m2) + esum4(a3, m2))) +
            ((esum4(a4, m2) + esum4(a5, m2)) + (esum4(a6, m2) + esum4(a7, m2)));
        s = fmaf(s, r, e);
        m = m2;
    }
    // remainder float4s (< UNROLL per thread)
    for (; i < nvec; i += BLOCK) {
        const float4 v = vp[i];
        const float mv = max4(v);
        const float m2 = fmaxf(m, mv);
        s = fmaf(s, __expf(m - m2), esum4(v, m2));
        m = m2;
    }
    // head scalars (<=3)
    for (int j = tid; j < head; j += BLOCK) {
        const float v = row_ptr[j];
        const float m2 = fmaxf(m, v);
        s = s * __expf(m - m2) + __expf(v - m2);
        m = m2;
    }
    // tail scalars (<=3)
    for (int j = tail_start + tid; j < V; j += BLOCK) {
        const float v = row_ptr[j];
        const float m2 = fmaxf(m, v);
        s = s * __expf(m - m2) + __expf(v - m2);
        m = m2;
    }
    // NB: every thread executes >= 1 main-loop chunk (nvec ~ 12563 >> 8*BLOCK bound
    // per-thread start), so m is finite here — no -inf/-inf NaN hazard in combine.

    // wave (64-lane) butterfly reduce
    for (int off = 32; off > 0; off >>= 1) {
        const float mo = __shfl_xor(m, off, 64);
        const float so = __shfl_xor(s, off, 64);
        combine(m, s, mo, so);
    }
    __shared__ float sm[BLOCK / 64], ss[BLOCK / 64];
    const int wave = tid >> 6;
    const int lane = tid & 63;
    if (lane == 0) { sm[wave] = m; ss[wave] = s; }
    __syncthreads();
    if (tid == 0) {
        m = sm[0]; s = ss[0];
        #pragma unroll
        for (int w = 1; w < BLOCK / 64; ++w) combine(m, s, sm[w], ss[w]);
        const float log_scale = logf((float)(1.0 - 0.154 + 0.154 / (double)V));
        // logp_t + log(scale)
        row_out[row] = (xt - m - logf(s)) + log_scale;
    }
}

__global__ __launch_bounds__(BLOCK) void sce_final_kernel(
    const float* __restrict__ row_vals, float* __restrict__ out, int n) {
    float sum = 0.0f;
    for (int i = threadIdx.x; i < n; i += BLOCK) sum += row_vals[i];
    for (int off = 32; off > 0; off >>= 1) sum += __shfl_xor(sum, off, 64);
    __shared__ float ssum[BLOCK / 64];
    const int wave = threadIdx.x >> 6;
    const int lane = threadIdx.x & 63;
    if (lane == 0) ssum[wave] = sum;
    __syncthreads();
    if (threadIdx.x == 0) {
        float t = 0.0f;
        #pragma unroll
        for (int w = 0; w < BLOCK / 64; ++w) t += ssum[w];
        out[0] = -t / (float)n;
    }
}

extern "C" void kernel_launch(void* const* d_in, const int* in_sizes, int n_in,
                              void* d_out, int out_size, void* d_ws, size_t ws_size,
                              hipStream_t stream) {
    const float* inputs = (const float*)d_in[0];
    const int* targets = (const int*)d_in[1];
    float* out = (float*)d_out;
    const int n = in_sizes[1];          // 4096 rows
    float* row_vals = (float*)d_ws;     // n floats of scratch (fully overwritten by kernel 1)

    sce_row_kernel<<<n, BLOCK, 0, stream>>>(inputs, targets, row_vals);
    sce_final_kernel<<<1, BLOCK, 0, stream>>>(row_vals, out, n);
}

// Round 3
// 991.337 us; speedup vs baseline: 1.0325x; 1.0325x over previous
//
#include <hip/hip_runtime.h>
#include <cstdint>
#include <cstddef>

#define V 50257
#define HALF0 25128          // split point: multiple of 8 floats
#define BLOCK 256
#define UNROLL 8

typedef float f32x4 __attribute__((ext_vector_type(4)));   // clang vector: OK for nontemporal builtin

__device__ __forceinline__ void combine(float& m, float& s, float mo, float so) {
    float m2 = fmaxf(m, mo);
    s = s * __expf(m - m2) + so * __expf(mo - m2);
    m = m2;
}

__device__ __forceinline__ float max4(const f32x4 v) {
    return fmaxf(fmaxf(v.x, v.y), fmaxf(v.z, v.w));
}

__device__ __forceinline__ float esum4(const f32x4 v, const float m2) {
    return (__expf(v.x - m2) + __expf(v.y - m2)) + (__expf(v.z - m2) + __expf(v.w - m2));
}

// One block per HALF-row: grid = 2*N. Consecutive blocks cover adjacent memory.
// Writes partial (m, s) per half; xt gathered by half 0.
__global__ __launch_bounds__(BLOCK) void sce_partial_kernel(
    const float* __restrict__ inputs, const int* __restrict__ targets,
    float* __restrict__ pm, float* __restrict__ ps, float* __restrict__ pxt) {
    const int bid = blockIdx.x;
    const int row = bid >> 1;
    const int half = bid & 1;
    const int tid = threadIdx.x;
    const float* row_ptr = inputs + (size_t)row * V;

    const int lo = half ? HALF0 : 0;
    const int hi = half ? V : HALF0;
    const float* ptr = row_ptr + lo;
    const int len = hi - lo;   // 25128 or 25129

    // target gather (half 0, thread 0; tiny, latency hidden under main loop)
    if (half == 0 && tid == 0) pxt[row] = row_ptr[targets[row]];

    // alignment: (row*V + lo) mod 4 rotates per row (V % 4 == 1)
    const int misalign = (int)(((size_t)row * V + (size_t)lo) & 3);
    const int head = (4 - misalign) & 3;
    const int nvec = (len - head) >> 2;            // ~6282 float4s
    const int tail_start = head + (nvec << 2);
    const f32x4* vp = reinterpret_cast<const f32x4*>(ptr + head);

    float m = -INFINITY, s = 0.0f;

    // main: 8-way unrolled chunked online softmax, nontemporal (streamed-once data)
    int i = tid;
    for (; i + (UNROLL - 1) * BLOCK < nvec; i += UNROLL * BLOCK) {
        const f32x4 a0 = __builtin_nontemporal_load(vp + i);
        const f32x4 a1 = __builtin_nontemporal_load(vp + i + 1 * BLOCK);
        const f32x4 a2 = __builtin_nontemporal_load(vp + i + 2 * BLOCK);
        const f32x4 a3 = __builtin_nontemporal_load(vp + i + 3 * BLOCK);
        const f32x4 a4 = __builtin_nontemporal_load(vp + i + 4 * BLOCK);
        const f32x4 a5 = __builtin_nontemporal_load(vp + i + 5 * BLOCK);
        const f32x4 a6 = __builtin_nontemporal_load(vp + i + 6 * BLOCK);
        const f32x4 a7 = __builtin_nontemporal_load(vp + i + 7 * BLOCK);

        const float cm = fmaxf(
            fmaxf(fmaxf(max4(a0), max4(a1)), fmaxf(max4(a2), max4(a3))),
            fmaxf(fmaxf(max4(a4), max4(a5)), fmaxf(max4(a6), max4(a7))));
        const float m2 = fmaxf(m, cm);
        const float r = __expf(m - m2);   // one rescale per 32 elements
        const float e =
            ((esum4(a0, m2) + esum4(a1, m2)) + (esum4(a2, m2) + esum4(a3, m2))) +
            ((esum4(a4, m2) + esum4(a5, m2)) + (esum4(a6, m2) + esum4(a7, m2)));
        s = fmaf(s, r, e);
        m = m2;
    }
    for (; i < nvec; i += BLOCK) {
        const f32x4 v = __builtin_nontemporal_load(vp + i);
        const float m2 = fmaxf(m, max4(v));
        s = fmaf(s, __expf(m - m2), esum4(v, m2));
        m = m2;
    }
    // head scalars (<=3)
    for (int j = tid; j < head; j += BLOCK) {
        const float v = ptr[j];
        const float m2 = fmaxf(m, v);
        s = s * __expf(m - m2) + __expf(v - m2);
        m = m2;
    }
    // tail scalars (<=3)
    for (int j = tail_start + tid; j < len; j += BLOCK) {
        const float v = ptr[j];
        const float m2 = fmaxf(m, v);
        s = s * __expf(m - m2) + __expf(v - m2);
        m = m2;
    }
    // nvec (~6282) covers thread starts up to (UNROLL-1)*BLOCK+tid via the two loops,
    // so every thread processed >=1 element -> m finite (no -inf/-inf NaN in reduce).

    // wave (64-lane) butterfly reduce
    for (int off = 32; off > 0; off >>= 1) {
        const float mo = __shfl_xor(m, off, 64);
        const float so = __shfl_xor(s, off, 64);
        combine(m, s, mo, so);
    }
    __shared__ float sm[BLOCK / 64], ss[BLOCK / 64];
    const int wave = tid >> 6;
    const int lane = tid & 63;
    if (lane == 0) { sm[wave] = m; ss[wave] = s; }
    __syncthreads();
    if (tid == 0) {
        m = sm[0]; s = ss[0];
        #pragma unroll
        for (int w = 1; w < BLOCK / 64; ++w) combine(m, s, sm[w], ss[w]);
        pm[bid] = m;
        ps[bid] = s;
    }
}

// Single block: merge half-partials, add log-scale, mean over rows.
__global__ __launch_bounds__(BLOCK) void sce_final_kernel(
    const float* __restrict__ pm, const float* __restrict__ ps,
    const float* __restrict__ pxt, float* __restrict__ out, int n) {
    const float log_scale = logf((float)(1.0 - 0.154 + 0.154 / (double)V));
    float sum = 0.0f;
    for (int r = threadIdx.x; r < n; r += BLOCK) {
        const float m0 = pm[2 * r],     s0 = ps[2 * r];
        const float m1 = pm[2 * r + 1], s1 = ps[2 * r + 1];
        const float mm = fmaxf(m0, m1);
        const float ssv = s0 * __expf(m0 - mm) + s1 * __expf(m1 - mm);
        sum += (pxt[r] - mm - logf(ssv)) + log_scale;
    }
    for (int off = 32; off > 0; off >>= 1) sum += __shfl_xor(sum, off, 64);
    __shared__ float ssum[BLOCK / 64];
    const int wave = threadIdx.x >> 6;
    const int lane = threadIdx.x & 63;
    if (lane == 0) ssum[wave] = sum;
    __syncthreads();
    if (threadIdx.x == 0) {
        float t = 0.0f;
        #pragma unroll
        for (int w = 0; w < BLOCK / 64; ++w) t += ssum[w];
        out[0] = -t / (float)n;
    }
}

extern "C" void kernel_launch(void* const* d_in, const int* in_sizes, int n_in,
                              void* d_out, int out_size, void* d_ws, size_t ws_size,
                              hipStream_t stream) {
    const float* inputs = (const float*)d_in[0];
    const int* targets = (const int*)d_in[1];
    float* out = (float*)d_out;
    const int n = in_sizes[1];              // 4096 rows

    // ws layout: pm[2n] | ps[2n] | pxt[n]  (fully overwritten each call)
    float* pm  = (float*)d_ws;
    float* ps  = pm + 2 * n;
    float* pxt = ps + 2 * n;

    sce_partial_kernel<<<2 * n, BLOCK, 0, stream>>>(inputs, targets, pm, ps, pxt);
    sce_final_kernel<<<1, BLOCK, 0, stream>>>(pm, ps, pxt, out, n);
}